// Round 8
// baseline (1957.629 us; speedup 1.0000x reference)
//
#include <hip/hip_runtime.h>
#include <math.h>

// ---------------------------------------------------------------------------
// Temporal GNN. Round 8: 128x256 GEMM tile (A fetched once per block-row),
// LayerNorm+PE fused into the FT GEMM epilogue (fp32 LN, no hi/lo pair, no
// separate ln_pe pass). f16 pipeline as round 7.
// ---------------------------------------------------------------------------

typedef __attribute__((ext_vector_type(8))) _Float16 half8;  // MFMA A/B frag
typedef __attribute__((ext_vector_type(4))) float floatx4;   // MFMA C/D

union HU { _Float16 h; unsigned short u; };

static __device__ __forceinline__ unsigned short f2h(float f) {
    HU x; x.h = (_Float16)f; return x.u;          // v_cvt_f16_f32 (RNE)
}
static __device__ __forceinline__ float h2f(unsigned short s) {
    HU x; x.u = s; return (float)x.h;
}

// async 16B/lane global -> LDS (dest = wave-uniform base + lane*16)
static __device__ __forceinline__ void gl_lds16(const void* g, void* l) {
    __builtin_amdgcn_global_load_lds(
        (const __attribute__((address_space(1))) unsigned int*)(g),
        (__attribute__((address_space(3))) unsigned int*)(l), 16, 0, 0);
}

// Split W[256][256] (k-major) into Bt'[n][768] = [Bh | Bl | Bh] f16 (transposed).
// grid (4,4,4): z = weight index. GCN GEMMs use only the first 512 columns.
__global__ void tg_splitB(const float* __restrict__ W0, const float* __restrict__ W1,
                          const float* __restrict__ W2, const float* __restrict__ W3,
                          unsigned short* __restrict__ B0, unsigned short* __restrict__ B1,
                          unsigned short* __restrict__ B2, unsigned short* __restrict__ B3)
{
    const float* Ws[4] = {W0, W1, W2, W3};
    unsigned short* Bs[4] = {B0, B1, B2, B3};
    const float* W = Ws[blockIdx.z];
    unsigned short* Bt = Bs[blockIdx.z];

    __shared__ float T[64][68];
    const int tk = blockIdx.x * 64, tn = blockIdx.y * 64;
    const int t = threadIdx.x;
#pragma unroll
    for (int j = 0; j < 4; ++j) {
        const int idx = t + 256 * j;
        const int k = idx >> 4, c4 = (idx & 15) * 4;
        const float4 v = *(const float4*)&W[(size_t)(tk + k) * 256 + tn + c4];
        T[k][c4] = v.x; T[k][c4 + 1] = v.y; T[k][c4 + 2] = v.z; T[k][c4 + 3] = v.w;
    }
    __syncthreads();
#pragma unroll
    for (int j = 0; j < 4; ++j) {
        const int idx = t + 256 * j;
        const int n = idx >> 4, q = (idx & 15) * 4;
        unsigned short hh[4], ll[4];
#pragma unroll
        for (int i = 0; i < 4; ++i) {
            const float f = T[q + i][n];
            hh[i] = f2h(f);
            ll[i] = f2h(f - h2f(hh[i]));
        }
        uint2 hp, lp;
        hp.x = (unsigned)hh[0] | ((unsigned)hh[1] << 16);
        hp.y = (unsigned)hh[2] | ((unsigned)hh[3] << 16);
        lp.x = (unsigned)ll[0] | ((unsigned)ll[1] << 16);
        lp.y = (unsigned)ll[2] | ((unsigned)ll[3] << 16);
        unsigned short* row = Bt + (size_t)(tn + n) * 768;
        *(uint2*)&row[tk + q]       = hp;   // Bh
        *(uint2*)&row[256 + tk + q] = lp;   // Bl
        *(uint2*)&row[512 + tk + q] = hp;   // Bh (pairs with Al, FT only)
    }
}

// Pre-split x[M][256] fp32 -> xh/xl f16 planes (zero pad rows >= N).
__global__ void tg_splitX(const float* __restrict__ x,
                          unsigned short* __restrict__ xh,
                          unsigned short* __restrict__ xl, int N, int Mpad)
{
    const int idx = blockIdx.x * 256 + threadIdx.x;
    const int r = idx >> 6, c4 = (idx & 63) * 4;
    if (r >= Mpad) return;
    ushort4 oh = {0, 0, 0, 0}, ol = {0, 0, 0, 0};
    if (r < N) {
        const float4 v = *(const float4*)&x[(size_t)r * 256 + c4];
        oh.x = f2h(v.x); ol.x = f2h(v.x - h2f(oh.x));
        oh.y = f2h(v.y); ol.y = f2h(v.y - h2f(oh.y));
        oh.z = f2h(v.z); ol.z = f2h(v.z - h2f(oh.z));
        oh.w = f2h(v.w); ol.w = f2h(v.w - h2f(oh.w));
    }
    *(ushort4*)&xh[(size_t)r * 256 + c4] = oh;
    *(ushort4*)&xl[(size_t)r * 256 + c4] = ol;
}

// 128x256-tile GEMM, 512 threads (8 waves, each one 64x64 subtile).
// Chunk c: A plane = (c<8) ? Ph : Pl at k=(c&3)*64 ; B' at k=c*64.
//   mode 0 (FT, nc=12): epilogue = bias+relu -> fused LayerNorm+PE -> f16 out.
//   mode 1 (GCN, nc=8): epilogue = f16(acc * rowscale[row]) -> out.
__global__ __launch_bounds__(512, 4)
void tg_gemm(const unsigned short* __restrict__ Ph,
             const unsigned short* __restrict__ Pl,
             const unsigned short* __restrict__ Bt,
             const float* __restrict__ bias, const float* __restrict__ rowscale,
             const float* __restrict__ ln_g, const float* __restrict__ ln_b,
             unsigned short* __restrict__ out,
             int M, int mode, int nc)
{
    __shared__ unsigned short sA[128 * 64];   // 16 KB
    __shared__ unsigned short sB[256 * 64];   // 32 KB
    __shared__ float lnsum[128], lnsq[128];

    const int t = threadIdx.x;
    const int w = t >> 6, lane = t & 63;
    const int quad = lane >> 4, l16 = lane & 15;
    const int wr = w & 1, wc = w >> 1;        // 2 row-groups x 4 col-groups
    const int row0 = blockIdx.x * 128;

    floatx4 acc[4][4];
#pragma unroll
    for (int i = 0; i < 4; ++i)
#pragma unroll
        for (int j = 0; j < 4; ++j) acc[i][j] = (floatx4){0.f, 0.f, 0.f, 0.f};

    // staging decode: 8 lanes per LDS row, slot (lane&7) holds kg = slot ^ (row&7)
    const int srow = lane >> 3;
    const int kgx  = (lane & 7) ^ srow;
    const int rsw  = l16 & 7;

    if (mode == 0 && t < 128) { lnsum[t] = 0.f; lnsq[t] = 0.f; }

    for (int c = 0; c < nc; ++c) {
        const unsigned short* Pa = (c < 8) ? Ph : Pl;
        const int ka = (c & 3) * 64;
        const int kb = c * 64;
        if (c) __syncthreads();
#pragma unroll
        for (int i = 0; i < 2; ++i) {         // A: 16 rows per wave
            const int r = w * 16 + i * 8;
            gl_lds16(Pa + (size_t)(row0 + r + srow) * 256 + ka + kgx * 8, &sA[r * 64]);
        }
#pragma unroll
        for (int i = 0; i < 4; ++i) {         // B: 32 cols per wave
            const int n = w * 32 + i * 8;
            gl_lds16(Bt + (size_t)(n + srow) * 768 + kb + kgx * 8, &sB[n * 64]);
        }
        __syncthreads();

#pragma unroll
        for (int ks = 0; ks < 2; ++ks) {
            const int kq = ks * 4 + quad;
            half8 af[4], bfr[4];
#pragma unroll
            for (int rt = 0; rt < 4; ++rt) {
                const int r = wr * 64 + rt * 16 + l16;
                af[rt] = *(const half8*)&sA[r * 64 + ((kq ^ rsw) * 8)];
            }
#pragma unroll
            for (int ct = 0; ct < 4; ++ct) {
                const int n = wc * 64 + ct * 16 + l16;
                bfr[ct] = *(const half8*)&sB[n * 64 + ((kq ^ rsw) * 8)];
            }
#pragma unroll
            for (int ct = 0; ct < 4; ++ct)
#pragma unroll
                for (int rt = 0; rt < 4; ++rt)
                    acc[rt][ct] = __builtin_amdgcn_mfma_f32_16x16x32_f16(
                        af[rt], bfr[ct], acc[rt][ct], 0, 0, 0);
        }
    }

    if (mode == 1) {   // GCN: f16(acc * rowscale)
#pragma unroll
        for (int rt = 0; rt < 4; ++rt) {
#pragma unroll
            for (int i = 0; i < 4; ++i) {
                const int gr = row0 + wr * 64 + rt * 16 + quad * 4 + i;
                const float s = rowscale[gr];
#pragma unroll
                for (int ct = 0; ct < 4; ++ct) {
                    const int gc = wc * 64 + ct * 16 + l16;
                    out[(size_t)gr * 256 + gc] = f2h(acc[rt][ct][i] * s);
                }
            }
        }
        return;
    }

    // ---- FT: bias + relu (in place), accumulate LN stats ----
    __syncthreads();   // lnsum/lnsq zero-init visible
#pragma unroll
    for (int rt = 0; rt < 4; ++rt) {
#pragma unroll
        for (int i = 0; i < 4; ++i) {
            const int rl = wr * 64 + rt * 16 + quad * 4 + i;   // local row
            float s4 = 0.f, q4 = 0.f;
#pragma unroll
            for (int ct = 0; ct < 4; ++ct) {
                const int gc = wc * 64 + ct * 16 + l16;
                float v = fmaxf(acc[rt][ct][i] + bias[gc], 0.f);
                acc[rt][ct][i] = v;
                s4 += v;
                q4 += v * v;
            }
            atomicAdd(&lnsum[rl], s4);
            atomicAdd(&lnsq[rl], q4);
        }
    }
    __syncthreads();
    if (t < 128) {
        const float mu = lnsum[t] * (1.f / 256.f);
        const float var = lnsq[t] * (1.f / 256.f) - mu * mu;
        lnsum[t] = mu;
        lnsq[t]  = 1.f / sqrtf(var + 1e-5f);
    }
    __syncthreads();

    // ---- normalize + PE + store single f16 plane ----
    const float cexp = -0.035977892078031970f;  // -log(10000)/256
    const int par = l16 & 1;                    // column parity (sin/cos)
#pragma unroll
    for (int ct = 0; ct < 4; ++ct) {
        const int gc = wc * 64 + ct * 16 + l16;
        const float gg = ln_g[gc];
        const float bb = ln_b[gc];
        const float div = expf((float)(gc & ~1) * cexp);
#pragma unroll
        for (int rt = 0; rt < 4; ++rt) {
#pragma unroll
            for (int i = 0; i < 4; ++i) {
                const int rl = wr * 64 + rt * 16 + quad * 4 + i;
                const int gr = row0 + rl;
                if (gr >= M) continue;
                const float ang = (float)gr * div;
                const float pe = par ? cosf(ang) : sinf(ang);
                const float v = (acc[rt][ct][i] - lnsum[rl]) * lnsq[rl] * gg + bb + pe;
                out[(size_t)gr * 256 + gc] = f2h(v);
            }
        }
    }
}

__global__ void tg_count(const int* __restrict__ dst, int* __restrict__ deg, int E)
{
    const int e = blockIdx.x * blockDim.x + threadIdx.x;
    if (e < E) atomicAdd(&deg[dst[e]], 1);
}

__global__ void tg_dinv(const int* __restrict__ deg, float* __restrict__ dinv, int N)
{
    const int i = blockIdx.x * blockDim.x + threadIdx.x;
    if (i < N) dinv[i] = 1.f / sqrtf((float)(deg[i] + 1));  // +1 self-loop
}

__global__ void tg_scan1(const int* __restrict__ cnt, int* __restrict__ out,
                         int* __restrict__ sums, int N)
{
    __shared__ int tmp[1024];
    const int t = threadIdx.x;
    const int gid = blockIdx.x * 1024 + t;
    const int v = (gid < N) ? cnt[gid] : 0;
    tmp[t] = v;
    __syncthreads();
    for (int o = 1; o < 1024; o <<= 1) {
        const int add = (t >= o) ? tmp[t - o] : 0;
        __syncthreads();
        tmp[t] += add;
        __syncthreads();
    }
    if (gid < N) out[gid] = tmp[t] - v;
    if (t == 1023) sums[blockIdx.x] = tmp[t];
}

__global__ void tg_scan2(int* __restrict__ sums, int nb)
{
    __shared__ int tmp[1024];
    const int t = threadIdx.x;
    const int v = (t < nb) ? sums[t] : 0;
    tmp[t] = v;
    __syncthreads();
    for (int o = 1; o < 1024; o <<= 1) {
        const int add = (t >= o) ? tmp[t - o] : 0;
        __syncthreads();
        tmp[t] += add;
        __syncthreads();
    }
    if (t < nb) sums[t] = tmp[t] - v;
}

__global__ void tg_scan3(int* __restrict__ rowptr, const int* __restrict__ offs,
                         int N, int E)
{
    const int gid = blockIdx.x * 1024 + threadIdx.x;
    if (gid < N) rowptr[gid] += offs[gid >> 10];
    else if (gid == N) rowptr[N] = E;
}

__global__ void tg_fill(const int* __restrict__ src, const int* __restrict__ dst,
                        const int* __restrict__ rowptr, int* __restrict__ cursor,
                        int* __restrict__ col, int E)
{
    const int e = blockIdx.x * blockDim.x + threadIdx.x;
    if (e >= E) return;
    const int d = dst[e];
    const int p = atomicAdd(&cursor[d], 1);
    col[rowptr[d] + p] = src[e];
}

// out = relu(dinv[i]*(hwp[i] + sum hwp[src]) + bias): f16 in, single f16 out.
__global__ void tg_aggregate_h(const unsigned short* __restrict__ hwpb,
                               const int* __restrict__ rowptr, const int* __restrict__ col,
                               const float* __restrict__ dinv, const float* __restrict__ bias,
                               unsigned short* __restrict__ hh, int N)
{
    const int row = (blockIdx.x * blockDim.x + threadIdx.x) >> 6;
    if (row >= N) return;
    const int lane = threadIdx.x & 63;
    const int c = lane * 4;
    const unsigned short* base = hwpb + c;
    const ushort4 sv = *(const ushort4*)(base + (size_t)row * 256);
    float a0 = h2f(sv.x), a1 = h2f(sv.y), a2 = h2f(sv.z), a3 = h2f(sv.w);
    const int beg = rowptr[row], end = rowptr[row + 1];
    int p = beg;
    for (; p + 8 <= end; p += 8) {
        ushort4 v[8];
#pragma unroll
        for (int u = 0; u < 8; ++u)
            v[u] = *(const ushort4*)(base + (size_t)col[p + u] * 256);
#pragma unroll
        for (int u = 0; u < 8; ++u) {
            a0 += h2f(v[u].x); a1 += h2f(v[u].y);
            a2 += h2f(v[u].z); a3 += h2f(v[u].w);
        }
    }
    for (; p < end; ++p) {
        const ushort4 v = *(const ushort4*)(base + (size_t)col[p] * 256);
        a0 += h2f(v.x); a1 += h2f(v.y); a2 += h2f(v.z); a3 += h2f(v.w);
    }
    const float di = dinv[row];
    const float4 bb = *(const float4*)&bias[c];
    ushort4 o;
    o.x = f2h(fmaxf(di * a0 + bb.x, 0.f));
    o.y = f2h(fmaxf(di * a1 + bb.y, 0.f));
    o.z = f2h(fmaxf(di * a2 + bb.z, 0.f));
    o.w = f2h(fmaxf(di * a3 + bb.w, 0.f));
    *(ushort4*)&hh[(size_t)row * 256 + c] = o;
}

__global__ void tg_ranges(const int* __restrict__ batch, int* __restrict__ starts,
                          int N, int G)
{
    const int g = blockIdx.x * blockDim.x + threadIdx.x;
    if (g > G) return;
    int lo = 0, hi = N;
    while (lo < hi) {
        const int mid = (lo + hi) >> 1;
        if (batch[mid] < g) lo = mid + 1; else hi = mid;
    }
    starts[g] = lo;
}

// Mean-pool: block per graph, 4 waves split rows, lane owns 4 channels.
__global__ void tg_pool(const unsigned short* __restrict__ hh,
                        const int* __restrict__ starts, float* __restrict__ pooled, int G)
{
    __shared__ float sh[4][64][4];
    const int g = blockIdx.x;
    const int t = threadIdx.x;
    const int wv = t >> 6, lane = t & 63;
    const int c = lane * 4;
    const int beg = starts[g], end = starts[g + 1];
    float s0 = 0.f, s1 = 0.f, s2 = 0.f, s3 = 0.f;
    for (int r = beg + wv; r < end; r += 4) {
        const ushort4 vh = *(const ushort4*)&hh[(size_t)r * 256 + c];
        s0 += h2f(vh.x); s1 += h2f(vh.y); s2 += h2f(vh.z); s3 += h2f(vh.w);
    }
    sh[wv][lane][0] = s0; sh[wv][lane][1] = s1;
    sh[wv][lane][2] = s2; sh[wv][lane][3] = s3;
    __syncthreads();
    if (t < 64) {
        const float inv = 1.f / fmaxf((float)(end - beg), 1.f);
        float4 o;
        o.x = (sh[0][t][0] + sh[1][t][0] + sh[2][t][0] + sh[3][t][0]) * inv;
        o.y = (sh[0][t][1] + sh[1][t][1] + sh[2][t][1] + sh[3][t][1]) * inv;
        o.z = (sh[0][t][2] + sh[1][t][2] + sh[2][t][2] + sh[3][t][2]) * inv;
        o.w = (sh[0][t][3] + sh[1][t][3] + sh[2][t][3] + sh[3][t][3]) * inv;
        *(float4*)&pooled[(size_t)g * 256 + t * 4] = o;
    }
}

__global__ void tg_mlp(const float* __restrict__ A, const float* __restrict__ B,
                       const float* __restrict__ bias, float* __restrict__ Cout,
                       int M, int K, int Nc, int do_relu)
{
    const int idx = blockIdx.x * blockDim.x + threadIdx.x;
    if (idx >= M * Nc) return;
    const int m = idx / Nc;
    const int n = idx - m * Nc;
    float acc = 0.f;
    for (int k = 0; k < K; ++k) acc += A[(size_t)m * K + k] * B[(size_t)k * Nc + n];
    acc += bias[n];
    Cout[idx] = do_relu ? fmaxf(acc, 0.f) : acc;
}

extern "C" void kernel_launch(void* const* d_in, const int* in_sizes, int n_in,
                              void* d_out, int out_size, void* d_ws, size_t ws_size,
                              hipStream_t stream)
{
    const float* x    = (const float*)d_in[0];
    const float* W_ft = (const float*)d_in[1];
    const float* b_ft = (const float*)d_in[2];
    const float* ln_g = (const float*)d_in[3];
    const float* ln_b = (const float*)d_in[4];
    const float* W_g[3] = {(const float*)d_in[5], (const float*)d_in[7], (const float*)d_in[9]};
    const float* b_g[3] = {(const float*)d_in[6], (const float*)d_in[8], (const float*)d_in[10]};
    const float* W_c0 = (const float*)d_in[11];
    const float* b_c0 = (const float*)d_in[12];
    const float* W_c1 = (const float*)d_in[13];
    const float* b_c1 = (const float*)d_in[14];
    const float* W_c2 = (const float*)d_in[15];
    const float* b_c2 = (const float*)d_in[16];
    const int*   edge  = (const int*)d_in[17];
    const int*   batch = (const int*)d_in[18];

    const int N    = in_sizes[18];        // 100000
    const int E    = in_sizes[17] / 2;    // 1600000
    const int Mpad = (N + 127) & ~127;    // 100096
    const int H2   = in_sizes[14];        // 128
    const int Cc   = in_sizes[15] / H2;   // 4
    const int G    = out_size / Cc;       // 512

    const int* srcI = edge;
    const int* dstI = edge + E;

    size_t off = 0;
    auto alloc = [&](size_t bytes) {
        char* p = (char*)d_ws + off;
        off = (off + bytes + 255) & ~(size_t)255;
        return p;
    };
    unsigned short* hh   = (unsigned short*)alloc((size_t)Mpad * 256 * 2);
    unsigned short* hwpb = (unsigned short*)alloc((size_t)Mpad * 256 * 2); // aliases xh
    unsigned short* xl   = (unsigned short*)alloc((size_t)Mpad * 256 * 2);
    unsigned short* xh   = hwpb;  // x hi-plane lives in hwpb until FT GEMM done
    float* dinv   = (float*)alloc((size_t)Mpad * 4);
    int*   deg    = (int*)alloc((size_t)Mpad * 4);
    int*   rowptr = (int*)alloc((size_t)(N + 1) * 4);
    int*   cursor = (int*)alloc((size_t)N * 4);
    int*   col    = (int*)alloc((size_t)E * 4);
    int*   bsums  = (int*)alloc(1024 * 4);
    int*   starts = (int*)alloc((size_t)(G + 1) * 4);
    float* pooled = (float*)alloc((size_t)G * 256 * 4);
    float* z0     = (float*)alloc((size_t)G * 256 * 4);
    float* z1     = (float*)alloc((size_t)G * H2 * 4);
    unsigned short* Bt[4];
    for (int i = 0; i < 4; ++i)
        Bt[i] = (unsigned short*)alloc((size_t)256 * 768 * 2);
    (void)ws_size; (void)n_in;

    hipMemsetAsync(deg, 0, (size_t)Mpad * 4, stream);
    hipMemsetAsync(cursor, 0, (size_t)N * 4, stream);
    // zero pad rows of hh (FT epilogue writes only rows < N; GCN GEMM reads pads)
    hipMemsetAsync(hh + (size_t)N * 256, 0, (size_t)(Mpad - N) * 256 * 2, stream);

    // 0. weight prep + x split
    tg_splitB<<<dim3(4, 4, 4), dim3(256), 0, stream>>>(
        W_ft, W_g[0], W_g[1], W_g[2], Bt[0], Bt[1], Bt[2], Bt[3]);
    tg_splitX<<<dim3(Mpad / 4), dim3(256), 0, stream>>>(x, xh, xl, N, Mpad);

    const dim3 GG(Mpad / 128);
    // 1+2. feature transform + fused LayerNorm + PE -> single f16 plane hh
    tg_gemm<<<GG, dim3(512), 0, stream>>>(xh, xl, Bt[0], b_ft, nullptr,
                                          ln_g, ln_b, hh, N, 0, 12);
    // 3. degrees + CSR build (rows = dst, cols = src)
    tg_count<<<dim3((E + 255) / 256), dim3(256), 0, stream>>>(dstI, deg, E);
    tg_dinv<<<dim3((Mpad + 255) / 256), dim3(256), 0, stream>>>(deg, dinv, Mpad);
    const int NB = (N + 1023) / 1024;
    tg_scan1<<<dim3(NB), dim3(1024), 0, stream>>>(deg, rowptr, bsums, N);
    tg_scan2<<<dim3(1), dim3(1024), 0, stream>>>(bsums, NB);
    tg_scan3<<<dim3((N + 1024) / 1024), dim3(1024), 0, stream>>>(rowptr, bsums, N, E);
    tg_fill<<<dim3((E + 255) / 256), dim3(256), 0, stream>>>(srcI, dstI, rowptr, cursor, col, E);
    // 4. GCN layers: hwpb = f16((h@W)*dinv) (K'=512); h = relu(dinv*sum + b)
    for (int l = 0; l < 3; ++l) {
        tg_gemm<<<GG, dim3(512), 0, stream>>>(hh, hh, Bt[l + 1], nullptr, dinv,
                                              nullptr, nullptr, hwpb, Mpad, 1, 8);
        tg_aggregate_h<<<dim3((N + 3) / 4), dim3(256), 0, stream>>>(hwpb, rowptr, col, dinv,
                                                                    b_g[l], hh, N);
    }
    // 5. per-graph mean pool
    tg_ranges<<<dim3((G + 256) / 256), dim3(256), 0, stream>>>(batch, starts, N, G);
    tg_pool<<<dim3(G), dim3(256), 0, stream>>>(hh, starts, pooled, G);
    // 6. classifier MLP
    tg_mlp<<<dim3((G * 256 + 255) / 256), dim3(256), 0, stream>>>(pooled, W_c0, b_c0, z0, G, 256, 256, 1);
    tg_mlp<<<dim3((G * H2 + 255) / 256), dim3(256), 0, stream>>>(z0, W_c1, b_c1, z1, G, 256, H2, 1);
    tg_mlp<<<dim3((G * Cc + 255) / 256), dim3(256), 0, stream>>>(z1, W_c2, b_c2, (float*)d_out, G, H2, Cc, 0);
}